// Round 10
// baseline (167.882 us; speedup 1.0000x reference)
//
#include <hip/hip_runtime.h>
#include <hip/hip_bf16.h>

// ---------- types ----------
typedef __attribute__((ext_vector_type(8))) short bf16x8;   // 4 VGPR MFMA A/B frag
typedef __attribute__((ext_vector_type(4))) short bf16x4;   // 8B packed store
typedef __attribute__((ext_vector_type(4))) float f32x4;    // 4 VGPR MFMA C/D frag

__device__ __forceinline__ unsigned short f2bf(float f) {
    __hip_bfloat16 h = __float2bfloat16(f);   // RNE
    return __builtin_bit_cast(unsigned short, h);
}
__device__ __forceinline__ void waitlgkm0() {
    asm volatile("s_waitcnt lgkmcnt(0)" ::: "memory");
}

// Problem constants: B=16, C=768, H=W=48 -> HW=2304, tokens/mod = 36864
#define BT 64             // tokens per block
#define TPM 576           // tiles per modality = 36864/64
#define NCHUNK 24         // 768 / 32

// ---------- single merged prep kernel (one launch instead of three) ----------
// Blocks 0..71: pack g*W1 -> bf16 MFMA B-fragment order
//   w1f[m][kk(24)][nf(12)][lane(64)][8]; lane l holds B[k=(l>>4)*8+j][n=l&15].
// Blocks 72..74: u[d] = sum_c g[c]*W1[c][d], vb[d] = sum_c b[c]*W1[c][d] + B1[d]
__global__ void prep_all(const float* __restrict__ w1, const float* __restrict__ lng,
                         const float* __restrict__ lnb, const float* __restrict__ b1,
                         unsigned short* __restrict__ w1f,
                         float* __restrict__ u, float* __restrict__ vb)
{
    const int b   = blockIdx.x;
    const int tid = threadIdx.x;          // 256 threads
    if (b < 72) {
        const int m  = b / 24;
        const int kk = b % 24;
        __shared__ float ws[32 * 192];
        const float* w1m = w1 + ((size_t)m * 768 + kk * 32) * 192;
        const float* gm  = lng + m * 768 + kk * 32;
        for (int i = tid; i < 6144; i += 256) {
            int cl = i / 192, d = i % 192;
            ws[i] = gm[cl] * w1m[(size_t)cl * 192 + d];
        }
        __syncthreads();
        unsigned short* outp = w1f + ((size_t)m * 24 + kk) * 6144;
        for (int i = tid; i < 6144; i += 256) {
            int nf   = i >> 9;
            int rem  = i & 511;
            int lane = rem >> 3;
            int j    = rem & 7;
            int cl   = ((lane >> 4) << 3) + j;
            int d    = (nf << 4) + (lane & 15);
            outp[i]  = f2bf(ws[cl * 192 + d]);
        }
    } else {
        const int m = b - 72;
        if (tid < 192) {
            const int d = tid;
            const float* w1m = w1 + (size_t)m * 768 * 192;
            const float* gm  = lng + m * 768;
            const float* bm  = lnb + m * 768;
            float su = 0.f, sv = 0.f;
            #pragma unroll 16
            for (int c = 0; c < 768; ++c) {
                float wv = w1m[(size_t)c * 192 + d];
                su += gm[c] * wv;
                sv += bm[c] * wv;
            }
            u[m * 192 + d]  = su;
            vb[m * 192 + d] = sv + b1[m * 192 + d];
        }
    }
}

// ---------- fused main kernel ----------
// 256 thr (4 waves), 64 tokens/block, TARGET 4 blocks/CU (launch_bounds(256,4)
// = 4 waves/SIMD = 16 waves/CU; VGPR must fit 128). Wave w owns d-slice
// [w*48,+48) (3 n-frags) over all 64 tokens (4 m-frags); loads ch [w*8,+8).
//
// K-loop, ONE raw barrier per step (loads cross it; only lgkm drained):
//   pack(k): read av regs (compiler inserts counted vmcnt), stats,
//            bf16 -> Atile[k&1] (XOR-swizzled slots)
//   LOADA(k+2) -> av (regs freed by pack)
//   lgkm0; s_barrier           (Atile[k&1] visible; loads still in flight)
//   frag-read Atile[k&1], 12x MFMA with bf
//   LOADB(k+1) -> bf           (regs freed by MFMA; L2-hot, 1-step lead)
//
// Atile WAR safety with double buffer + 1 barrier/step: wave Y's ds_reads of
// Atile[k&1] (step k) retire before Y's MFMA(k) issue (lgkm wait), which
// precedes Y's barrier(k+1) arrival; wave X's pack(k+2) rewrite of Atile[k&1]
// occurs after X passes barrier(k+1). Hence reads(k) globally precede
// writes(k+2). av/bf register WAR: consumer precedes re-load in program
// order; compiler enforces via dependency tracking.
__global__ __launch_bounds__(256, 4)
void fused_main(const float* __restrict__ f0, const float* __restrict__ f1,
                const float* __restrict__ f2,
                const unsigned short* __restrict__ w1f,
                const float* __restrict__ u_g, const float* __restrict__ vb_g,
                const float* __restrict__ w2_g, const float* __restrict__ b2_g,
                float* __restrict__ out)
{
    // XCD-aware swizzle: 1728 = 8 * 216 exactly (bijective).
    const int bx0  = blockIdx.x;
    const int bx   = (bx0 & 7) * 216 + (bx0 >> 3);
    const int mod  = bx / TPM;
    const int tile = bx % TPM;
    const float* feat = (mod == 0) ? f0 : ((mod == 1) ? f1 : f2);
    const int T0   = tile * BT;
    const int bimg = T0 / 2304;
    const int hw0  = T0 % 2304;               // 64 | 2304: no image crossing
    const float* fbase = feat + (size_t)bimg * 768 * 2304 + hw0;

    const int tid = threadIdx.x;
    const int l   = tid & 63;
    const int w   = tid >> 6;     // wave 0..3
    const int p   = l & 31;       // token pair 2p, 2p+1 (pack phase)
    const int cg  = l >> 5;       // 4-ch half of this wave's 8-ch slot
    const int col = l & 15, lg = l >> 4;

    __shared__ unsigned short Atile[2][64][40];  // 10 KB, slot-XOR swizzle
    __shared__ float redS[4][64], redQ[4][64];   // 2 KB
    __shared__ float mu_s[64], rs_s[64];         // 0.5 KB
    __shared__ float red2[4][64];                // 1 KB   (total ~13.8 KB)

    const unsigned short* w1fm = w1f + (size_t)mod * 24 * 6144;

    f32x4 acc[4][3];
    #pragma unroll
    for (int a = 0; a < 4; ++a)
        #pragma unroll
        for (int b = 0; b < 3; ++b) acc[a][b] = (f32x4){0.f, 0.f, 0.f, 0.f};

    float sum0 = 0.f, ssq0 = 0.f, sum1 = 0.f, ssq1 = 0.f;

    float2 avA[4], avB[4];
    bf16x8 bf[3];

    auto LOADA = [&](float2 (&av)[4], int kk) {
        const float* sA = fbase + (size_t)(kk * 32 + w * 8 + cg * 4) * 2304 + 2 * p;
        #pragma unroll
        for (int j = 0; j < 4; ++j)
            av[j] = *reinterpret_cast<const float2*>(sA + (size_t)j * 2304);
    };
    auto LOADB = [&](int kk) {
        const bf16x8* sB = reinterpret_cast<const bf16x8*>(w1fm + (size_t)kk * 6144);
        #pragma unroll
        for (int nf = 0; nf < 3; ++nf)
            bf[nf] = sB[(w * 3 + nf) * 64 + l];      // 16B/lane, L2-hot
    };

    auto STEP = [&](float2 (&av)[4], int kk) {
        const int buf = kk & 1;
        // ---- pack: av regs -> stats + bf16 Atile[buf] ----
        const int t0 = 2 * p, t1 = t0 + 1;
        const int s0 = w ^ (((t0 >> 2) ^ (t0 >> 4)) & 3);
        const int s1 = w ^ (((t1 >> 2) ^ (t1 >> 4)) & 3);
        bf16x4 q0, q1;
        #pragma unroll
        for (int j = 0; j < 4; ++j) {
            float x0 = av[j].x, x1 = av[j].y;
            q0[j] = (short)f2bf(x0);
            q1[j] = (short)f2bf(x1);
            sum0 += x0; ssq0 = fmaf(x0, x0, ssq0);
            sum1 += x1; ssq1 = fmaf(x1, x1, ssq1);
        }
        *reinterpret_cast<bf16x4*>(&Atile[buf][t0][s0 * 8 + cg * 4]) = q0;
        *reinterpret_cast<bf16x4*>(&Atile[buf][t1][s1 * 8 + cg * 4]) = q1;
        // ---- prefetch A two steps ahead into just-freed regs ----
        if (kk < NCHUNK - 2) LOADA(av, kk + 2);
        // ---- raw barrier: LDS visible, global loads stay in flight ----
        waitlgkm0();
        __builtin_amdgcn_sched_barrier(0);
        __builtin_amdgcn_s_barrier();
        __builtin_amdgcn_sched_barrier(0);
        // ---- fragments + MFMA ----
        bf16x8 af[4];
        #pragma unroll
        for (int mf = 0; mf < 4; ++mf) {
            int t = mf * 16 + col;
            int s = lg ^ (((t >> 2) ^ (t >> 4)) & 3);
            af[mf] = *reinterpret_cast<const bf16x8*>(&Atile[buf][t][s * 8]);
        }
        #pragma unroll
        for (int mf = 0; mf < 4; ++mf)
            #pragma unroll
            for (int nf = 0; nf < 3; ++nf)
                acc[mf][nf] = __builtin_amdgcn_mfma_f32_16x16x32_bf16(
                                  af[mf], bf[nf], acc[mf][nf], 0, 0, 0);
        // ---- B for next step (regs just consumed by MFMA) ----
        if (kk < NCHUNK - 1) LOADB(kk + 1);
    };

    LOADA(avA, 0);
    LOADA(avB, 1);
    LOADB(0);
    #pragma unroll 1
    for (int kt = 0; kt < NCHUNK / 2; ++kt) {
        STEP(avA, 2 * kt);
        STEP(avB, 2 * kt + 1);
    }

    // ---- LayerNorm stats (per token over all 768 ch) ----
    sum0 += __shfl_xor(sum0, 32);  sum1 += __shfl_xor(sum1, 32);
    ssq0 += __shfl_xor(ssq0, 32);  ssq1 += __shfl_xor(ssq1, 32);
    if (l < 32) {
        redS[w][2 * p] = sum0;  redS[w][2 * p + 1] = sum1;
        redQ[w][2 * p] = ssq0;  redQ[w][2 * p + 1] = ssq1;
    }
    __syncthreads();
    if (tid < 64) {
        float S = redS[0][tid] + redS[1][tid] + redS[2][tid] + redS[3][tid];
        float Q = redQ[0][tid] + redQ[1][tid] + redQ[2][tid] + redQ[3][tid];
        float mu = S * (1.f / 768.f);
        float var = Q * (1.f / 768.f) - mu * mu;
        mu_s[tid] = mu;
        rs_s[tid] = rsqrtf(var + 1e-5f);
    }
    __syncthreads();

    // ---- epilogue: affine LN fix + GELU + dot(w2) + sigmoid ----
    const float* um  = u_g  + mod * 192;
    const float* vbm = vb_g + mod * 192;
    const float* w2m = w2_g + mod * 192;
    float uf[3], vbf[3], w2f[3];
    #pragma unroll
    for (int nf = 0; nf < 3; ++nf) {
        int d = (w * 3 + nf) * 16 + col;
        uf[nf] = um[d]; vbf[nf] = vbm[d]; w2f[nf] = w2m[d];
    }
    float ps[4][4];
    #pragma unroll
    for (int mf = 0; mf < 4; ++mf) {
        #pragma unroll
        for (int r = 0; r < 4; ++r) {
            int t = mf * 16 + lg * 4 + r;   // C/D: row=(lane>>4)*4+reg
            float mu = mu_s[t], rs = rs_s[t];
            float pp = 0.f;
            #pragma unroll
            for (int nf = 0; nf < 3; ++nf) {
                float x = rs * (acc[mf][nf][r] - mu * uf[nf]) + vbf[nf];
                float h = 0.5f * x * (1.f + erff(x * 0.70710678118f));  // exact GELU
                pp += h * w2f[nf];
            }
            ps[mf][r] = pp;
        }
    }
    #pragma unroll
    for (int m = 1; m < 16; m <<= 1)
        #pragma unroll
        for (int mf = 0; mf < 4; ++mf)
            #pragma unroll
            for (int r = 0; r < 4; ++r)
                ps[mf][r] += __shfl_xor(ps[mf][r], m, 64);
    if (col == 0) {
        #pragma unroll
        for (int mf = 0; mf < 4; ++mf)
            #pragma unroll
            for (int r = 0; r < 4; ++r)
                red2[w][mf * 16 + lg * 4 + r] = ps[mf][r];
    }
    __syncthreads();
    if (tid < 64) {
        float logit = red2[0][tid] + red2[1][tid] + red2[2][tid] + red2[3][tid] + b2_g[mod];
        out[(size_t)mod * 36864 + T0 + tid] = 1.f / (1.f + expf(-logit));
    }
}

// ---------- launch ----------
extern "C" void kernel_launch(void* const* d_in, const int* in_sizes, int n_in,
                              void* d_out, int out_size, void* d_ws, size_t ws_size,
                              hipStream_t stream)
{
    const float* f0  = (const float*)d_in[0];
    const float* f1  = (const float*)d_in[1];
    const float* f2  = (const float*)d_in[2];
    const float* lng = (const float*)d_in[3];
    const float* lnb = (const float*)d_in[4];
    const float* w1  = (const float*)d_in[5];
    const float* b1  = (const float*)d_in[6];
    const float* w2  = (const float*)d_in[7];
    const float* b2  = (const float*)d_in[8];
    float* out = (float*)d_out;

    char* ws = (char*)d_ws;
    unsigned short* w1f = (unsigned short*)ws;          // 884736 B
    float* u     = (float*)(ws + 884736);               // 2304 B
    float* vb    = (float*)(ws + 887040);               // 2304 B

    prep_all  <<<dim3(75), dim3(256), 0, stream>>>(w1, lng, lnb, b1, w1f, u, vb);
    fused_main<<<dim3(3 * TPM), dim3(256), 0, stream>>>(f0, f1, f2, w1f, u, vb, w2, b2, out);
}